// Round 1
// baseline (947.412 us; speedup 1.0000x reference)
//
#include <hip/hip_runtime.h>
#include <hip/hip_bf16.h>

#define B_TOK 4096
#define DIM   2048
#define HID   4096
#define NEXP  8
#define CAP   4096

#define BM 256
#define BN 256
#define BK 32        /* bf16 elements per K tile; triple-buffered in LDS */
#define KITER (DIM / BK)   /* 64 */

typedef short  bf16x8 __attribute__((ext_vector_type(8)));
typedef unsigned short us16x8 __attribute__((ext_vector_type(8)));
typedef float  f32x4  __attribute__((ext_vector_type(4)));

__device__ __forceinline__ unsigned short f2bf(float f) {
    unsigned u = __builtin_bit_cast(unsigned, f);
    u += 0x7fffu + ((u >> 16) & 1u);          // round-to-nearest-even
    return (unsigned short)(u >> 16);
}

// async global -> LDS, 16 B per lane, LDS dest = wave-uniform base + lane*16
__device__ __forceinline__ void async_copy16(const void* g, void* l) {
    __builtin_amdgcn_global_load_lds(
        (const __attribute__((address_space(1))) unsigned*)g,
        (__attribute__((address_space(3))) unsigned*)l, 16, 0, 0);
}

// ---------------------------------------------------------------------------
// fp32 -> bf16 stream cast (expert_W only; x cast fused into gating)
// ---------------------------------------------------------------------------
__global__ __launch_bounds__(256) void cvt_kernel(
    const float* __restrict__ src, unsigned short* __restrict__ dst, long n) {
    long i = ((long)blockIdx.x * 256 + threadIdx.x) * 8;
    if (i >= n) return;
    float4 v0 = *(const float4*)(src + i);
    float4 v1 = *(const float4*)(src + i + 4);
    us16x8 o = { f2bf(v0.x), f2bf(v0.y), f2bf(v0.z), f2bf(v0.w),
                 f2bf(v1.x), f2bf(v1.y), f2bf(v1.z), f2bf(v1.w) };
    *(us16x8*)(dst + i) = o;
}

// ---------------------------------------------------------------------------
// c[n][e] = dot(emb[n], gate_W[e][D:2D]) + gate_b[e]   (24 waves total)
// ---------------------------------------------------------------------------
__global__ __launch_bounds__(256) void compute_c_kernel(
    const float* __restrict__ emb, const float* __restrict__ gate_W,
    const float* __restrict__ gate_b, float* __restrict__ cbuf) {
    int wave = (blockIdx.x * blockDim.x + threadIdx.x) >> 6;
    int lane = threadIdx.x & 63;
    if (wave >= 24) return;
    int n = wave >> 3, e = wave & 7;
    const float4* er = (const float4*)(emb + (size_t)n * DIM);
    const float4* wr = (const float4*)(gate_W + (size_t)e * 2 * DIM + DIM);
    float acc = 0.f;
    for (int c = lane; c < DIM / 4; c += 64) {
        float4 a = er[c], b = wr[c];
        acc += a.x * b.x + a.y * b.y + a.z * b.z + a.w * b.w;
    }
    #pragma unroll
    for (int off = 32; off; off >>= 1) acc += __shfl_down(acc, off, 64);
    if (lane == 0) cbuf[n * 8 + e] = acc + gate_b[e];
}

// ---------------------------------------------------------------------------
// Gating: one wave per token, fp32 (topk_idx must be exact). Also converts
// the token row to bf16 (fused x-cast). Writes expert dispatch lists with
// rank and per-token combine weights.
// ---------------------------------------------------------------------------
__global__ __launch_bounds__(256) void gating_kernel(
    const float* __restrict__ x, const int* __restrict__ labels,
    const float* __restrict__ gate_W, const float* __restrict__ cbuf,
    int* __restrict__ counts, int* __restrict__ tlist, int* __restrict__ rlist,
    float* __restrict__ wA, float* __restrict__ wB,
    unsigned short* __restrict__ xb, float* __restrict__ out_idx) {
    int wave = threadIdx.x >> 6, lane = threadIdx.x & 63;
    int b = blockIdx.x * 4 + wave;
    const float4* xr  = (const float4*)(x + (size_t)b * DIM);
    const float4* gw4 = (const float4*)gate_W;
    unsigned short* xo = xb + (size_t)b * DIM;
    float acc[8] = {0.f, 0.f, 0.f, 0.f, 0.f, 0.f, 0.f, 0.f};
    for (int c = lane; c < DIM / 4; c += 64) {
        float4 xv = xr[c];
        ushort4 xc = { f2bf(xv.x), f2bf(xv.y), f2bf(xv.z), f2bf(xv.w) };
        *(ushort4*)(xo + 4 * c) = xc;
        #pragma unroll
        for (int e = 0; e < 8; ++e) {
            float4 wv = gw4[e * (2 * DIM / 4) + c];
            acc[e] += xv.x * wv.x + xv.y * wv.y + xv.z * wv.z + xv.w * wv.w;
        }
    }
    #pragma unroll
    for (int off = 32; off; off >>= 1) {
        #pragma unroll
        for (int e = 0; e < 8; ++e) acc[e] += __shfl_down(acc[e], off, 64);
    }
    if (lane == 0) {
        int lbl = labels[b];
        float lg[8];
        #pragma unroll
        for (int e = 0; e < 8; ++e) lg[e] = acc[e] + cbuf[lbl * 8 + e];
        int e0 = 0; float t0 = lg[0];
        #pragma unroll
        for (int e = 1; e < 8; ++e) if (lg[e] > t0) { t0 = lg[e]; e0 = e; }
        int e1 = -1; float t1 = -1e30f;
        #pragma unroll
        for (int e = 0; e < 8; ++e)
            if (e != e0 && lg[e] > t1) { t1 = lg[e]; e1 = e; }
        float w0 = 1.f / (1.f + __expf(t1 - t0));
        float w1 = 1.f - w0;
        int p0 = atomicAdd(&counts[e0], 1);
        int p1 = atomicAdd(&counts[e1], 1);
        tlist[e0 * CAP + p0] = b; rlist[e0 * CAP + p0] = 0;
        tlist[e1 * CAP + p1] = b; rlist[e1 * CAP + p1] = 1;
        wA[b] = w0; wB[b] = w1;
        out_idx[2 * b]     = (float)e0;
        out_idx[2 * b + 1] = (float)e1;
    }
}

// ---------------------------------------------------------------------------
// Pad each expert list to a multiple of BM: token 0, rank 2 (-> weight 0).
// ---------------------------------------------------------------------------
__global__ void pad_kernel(const int* __restrict__ counts,
                           int* __restrict__ tlist, int* __restrict__ rlist) {
    int e = blockIdx.x, c = counts[e];
    int padded = (c + BM - 1) & ~(BM - 1);
    int i = c + threadIdx.x;
    if (i < padded) { tlist[e * CAP + i] = 0; rlist[e * CAP + i] = 2; }
}

// ---------------------------------------------------------------------------
// Grouped expert GEMM, 256x256 tile, BK=32, 8 waves (2Mx4N, 128x64 each).
// Triple-buffered LDS with distance-2 K-tile prefetch -> counted vmcnt(4)
// at the (single) per-K-tile barrier; loads never drain to 0 in the main
// loop. LDS is XOR-swizzled (byte ^= (row&3)<<4) via pre-swizzled global
// source + linear global_load_lds dest + swizzled ds_read (conflict-free
// b128 frag reads: 8 lanes per 16B slot, even over 32 banks). Epilogue
// fuses the combine: atomicAdd of w*(acc+bias) into out (pre-zeroed).
// ---------------------------------------------------------------------------
__global__ __launch_bounds__(512, 2) void moe_gemm_kernel(
    const unsigned short* __restrict__ xb, const unsigned short* __restrict__ Wb,
    const int* __restrict__ counts, const int* __restrict__ tlist,
    const int* __restrict__ rlist, const float* __restrict__ wA,
    const float* __restrict__ wB, const float* __restrict__ eb,
    float* __restrict__ out) {
    const int e  = blockIdx.z;
    const int m0 = blockIdx.y * BM;
    if (m0 >= counts[e]) return;
    const int n0 = blockIdx.x * BN;

    __shared__ unsigned short Abuf[3][BM * BK];   // 16 KB per slot
    __shared__ unsigned short Bbuf[3][BN * BK];
    __shared__ int   toks[BM];
    __shared__ float roww[BM];
    __shared__ unsigned long long rowp[BM];

    const int t = threadIdx.x;
    if (t < BM) {
        int tok = tlist[e * CAP + m0 + t];
        int rk  = rlist[e * CAP + m0 + t];
        toks[t] = tok;
        roww[t] = (rk == 0) ? wA[tok] : (rk == 1) ? wB[tok] : 0.f;
        rowp[t] = (unsigned long long)(out + (size_t)tok * HID);
    }
    __syncthreads();   // also drains the tlist/w loads before pipeline starts

    const int lane = t & 63, wv = t >> 6;
    const int r = lane & 15, quad = lane >> 4;
    const int wm = wv >> 2, wn = wv & 3;

    // staging: 2048 16B chunks per K-tile (1024 A + 1024 B), 4 per thread.
    // chunk d covers LDS bytes [d*16, d*16+16): row = d>>2, col-bytes
    // (d&3)*16; pre-swizzle the SOURCE by the read swizzle (involution).
    const unsigned short* gAsrc[2];
    const unsigned short* gBsrc[2];
    int ldsc[2];
    #pragma unroll
    for (int s = 0; s < 2; ++s) {
        int chunk = s * 512 + t;
        int row   = chunk >> 2;
        int csrc  = ((chunk & 3) << 4) ^ ((row & 3) << 4);   // byte in row
        gAsrc[s] = xb + (size_t)toks[row] * DIM + (csrc >> 1);
        gBsrc[s] = Wb + ((size_t)e * HID + n0 + row) * DIM + (csrc >> 1);
        ldsc[s]  = (s * 512 + wv * 64) * 8;                  // elems, wave-uniform
    }

    auto stage_half = [&](int slot, int kt, int s) {   // 2 loads / thread
        const int kc = kt * BK;
        async_copy16(gAsrc[s] + kc, &Abuf[slot][ldsc[s]]);
        async_copy16(gBsrc[s] + kc, &Bbuf[slot][ldsc[s]]);
    };

    const int fOff = (quad * 16) ^ ((r & 3) << 4);     // swizzled byte-in-row
    f32x4 acc[8][4] = {};

    // prologue: tiles 0,1 in flight; wait for tile 0 (4 newest stay out)
    stage_half(0, 0, 0); stage_half(0, 0, 1);
    stage_half(1, 1, 0); stage_half(1, 1, 1);
    asm volatile("s_waitcnt vmcnt(4)" ::: "memory");
    __builtin_amdgcn_s_barrier();
    __builtin_amdgcn_sched_barrier(0);

    int slot = 0, slot2 = 2;
    for (int kt = 0; kt < KITER; ++kt) {
        const bool pf = (kt + 2 < KITER);
        if (pf) stage_half(slot2, kt + 2, 0);

        const char* Ab = (const char*)&Abuf[slot][0];
        const char* Bb = (const char*)&Bbuf[slot][0];
        bf16x8 a[4], b[4];
        #pragma unroll
        for (int i = 0; i < 4; ++i)
            a[i] = *(const bf16x8*)(Ab + (wm * 128 + i * 16 + r) * 64 + fOff);
        #pragma unroll
        for (int j = 0; j < 4; ++j)
            b[j] = *(const bf16x8*)(Bb + (wn * 64 + j * 16 + r) * 64 + fOff);
        __builtin_amdgcn_s_setprio(1);
        #pragma unroll
        for (int i = 0; i < 4; ++i)
            #pragma unroll
            for (int j = 0; j < 4; ++j)
                acc[i][j] = __builtin_amdgcn_mfma_f32_16x16x32_bf16(
                    a[i], b[j], acc[i][j], 0, 0, 0);
        __builtin_amdgcn_s_setprio(0);

        if (pf) stage_half(slot2, kt + 2, 1);

        bf16x8 a2[4];
        #pragma unroll
        for (int i = 0; i < 4; ++i)
            a2[i] = *(const bf16x8*)(Ab + (wm * 128 + (i + 4) * 16 + r) * 64 + fOff);
        __builtin_amdgcn_s_setprio(1);
        #pragma unroll
        for (int i = 0; i < 4; ++i)
            #pragma unroll
            for (int j = 0; j < 4; ++j)
                acc[i + 4][j] = __builtin_amdgcn_mfma_f32_16x16x32_bf16(
                    a2[i], b[j], acc[i + 4][j], 0, 0, 0);
        __builtin_amdgcn_s_setprio(0);

        __builtin_amdgcn_sched_barrier(0);
        if (pf) asm volatile("s_waitcnt vmcnt(4)" ::: "memory"); // tile kt+1 landed
        else    asm volatile("s_waitcnt vmcnt(0)" ::: "memory"); // drain tail
        __builtin_amdgcn_s_barrier();
        __builtin_amdgcn_sched_barrier(0);

        slot  = (slot  == 2) ? 0 : slot  + 1;
        slot2 = (slot2 == 2) ? 0 : slot2 + 1;
    }

    // fused-combine epilogue: out[tok][col] += w * (acc + bias[e][col])
    #pragma unroll
    for (int j = 0; j < 4; ++j) {
        int col = n0 + wn * 64 + j * 16 + r;
        float bc = eb[(size_t)e * HID + col];
        #pragma unroll
        for (int i = 0; i < 8; ++i) {
            int rowb = wm * 128 + i * 16 + quad * 4;
            #pragma unroll
            for (int r4 = 0; r4 < 4; ++r4) {
                float w = roww[rowb + r4];
                if (w != 0.f)
                    atomicAdd((float*)rowp[rowb + r4] + col,
                              w * (acc[i][j][r4] + bc));
            }
        }
    }
}

// ---------------------------------------------------------------------------
extern "C" void kernel_launch(void* const* d_in, const int* in_sizes, int n_in,
                              void* d_out, int out_size, void* d_ws, size_t ws_size,
                              hipStream_t stream) {
    const float* x        = (const float*)d_in[0];
    const int*   labels   = (const int*)  d_in[1];
    const float* emb      = (const float*)d_in[2];
    const float* gate_W   = (const float*)d_in[3];
    const float* gate_b   = (const float*)d_in[4];
    const float* expert_W = (const float*)d_in[5];
    const float* expert_b = (const float*)d_in[6];
    float* out = (float*)d_out;

    char* ws = (char*)d_ws;
    int*   counts = (int*)ws;                                  // 32 B
    float* cbuf   = (float*)(ws + 256);                        // 96 B
    int*   tlist  = (int*)(ws + 512);                          // 131072 B
    int*   rlist  = (int*)(ws + 512 + 131072);                 // 131072 B
    float* wA     = (float*)(ws + 262656);                     // 16 KB
    float* wB     = (float*)(ws + 279040);                     // 16 KB
    unsigned short* xb = (unsigned short*)(ws + 295424);       // 16 MB
    unsigned short* Wb = xb + (size_t)B_TOK * DIM;             // 134 MB
    // total ws use ≈ 151.3 MiB

    hipMemsetAsync(counts, 0, 8 * sizeof(int), stream);
    hipMemsetAsync(out, 0, (size_t)B_TOK * HID * sizeof(float), stream);

    cvt_kernel<<<(NEXP * HID * DIM) / (8 * 256), 256, 0, stream>>>(
        expert_W, Wb, (long)NEXP * HID * DIM);
    compute_c_kernel<<<6, 256, 0, stream>>>(emb, gate_W, gate_b, cbuf);
    gating_kernel<<<B_TOK / 4, 256, 0, stream>>>(
        x, labels, gate_W, cbuf, counts, tlist, rlist, wA, wB, xb,
        out + (size_t)B_TOK * HID);
    pad_kernel<<<NEXP, BM, 0, stream>>>(counts, tlist, rlist);
    moe_gemm_kernel<<<dim3(HID / BN, B_TOK / BM, NEXP), 512, 0, stream>>>(
        xb, Wb, counts, tlist, rlist, wA, wB, expert_b, out);
}

// Round 2
// 746.191 us; speedup vs baseline: 1.2697x; 1.2697x over previous
//
#include <hip/hip_runtime.h>
#include <hip/hip_bf16.h>

#define B_TOK 4096
#define DIM   2048
#define HID   4096
#define NEXP  8
#define CAP   4224   /* 4096 + BM slack for padding */

#define BM 128
#define BN 128
#define BK 32        /* bf16 elements per K stage (dbuf: 2 stages in LDS) */
#define KITER (DIM / BK)

typedef short  bf16x8 __attribute__((ext_vector_type(8)));
typedef unsigned short us16x8 __attribute__((ext_vector_type(8)));
typedef float  f32x4  __attribute__((ext_vector_type(4)));

__device__ __forceinline__ unsigned short f2bf(float f) {
    unsigned u = __builtin_bit_cast(unsigned, f);
    u += 0x7fffu + ((u >> 16) & 1u);          // round-to-nearest-even
    return (unsigned short)(u >> 16);
}

// async global -> LDS, 16 B per lane, LDS dest = wave-uniform base + lane*16
__device__ __forceinline__ void async_copy16(const void* g, void* l) {
    __builtin_amdgcn_global_load_lds(
        (const __attribute__((address_space(1))) unsigned*)g,
        (__attribute__((address_space(3))) unsigned*)l, 16, 0, 0);
}

// ---------------------------------------------------------------------------
// fp32 -> bf16 stream cast (expert_W; x cast is fused into gating)
// ---------------------------------------------------------------------------
__global__ __launch_bounds__(256) void cvt_kernel(
    const float* __restrict__ src, unsigned short* __restrict__ dst, long n) {
    long i = ((long)blockIdx.x * 256 + threadIdx.x) * 8;
    if (i >= n) return;
    float4 v0 = *(const float4*)(src + i);
    float4 v1 = *(const float4*)(src + i + 4);
    us16x8 o = { f2bf(v0.x), f2bf(v0.y), f2bf(v0.z), f2bf(v0.w),
                 f2bf(v1.x), f2bf(v1.y), f2bf(v1.z), f2bf(v1.w) };
    *(us16x8*)(dst + i) = o;
}

// ---------------------------------------------------------------------------
// c[n][e] = dot(emb[n], gate_W[e][D:2D]) + gate_b[e]   (24 waves total)
// ---------------------------------------------------------------------------
__global__ __launch_bounds__(256) void compute_c_kernel(
    const float* __restrict__ emb, const float* __restrict__ gate_W,
    const float* __restrict__ gate_b, float* __restrict__ cbuf) {
    int wave = (blockIdx.x * blockDim.x + threadIdx.x) >> 6;
    int lane = threadIdx.x & 63;
    if (wave >= 24) return;
    int n = wave >> 3, e = wave & 7;
    const float4* er = (const float4*)(emb + (size_t)n * DIM);
    const float4* wr = (const float4*)(gate_W + (size_t)e * 2 * DIM + DIM);
    float acc = 0.f;
    for (int c = lane; c < DIM / 4; c += 64) {
        float4 a = er[c], b = wr[c];
        acc += a.x * b.x + a.y * b.y + a.z * b.z + a.w * b.w;
    }
    #pragma unroll
    for (int off = 32; off; off >>= 1) acc += __shfl_down(acc, off, 64);
    if (lane == 0) cbuf[n * 8 + e] = acc + gate_b[e];
}

// ---------------------------------------------------------------------------
// Gating: one wave per token, fp32 (topk_idx must be exact). Also converts
// the token row to bf16 (fused x-cast). Writes expert dispatch lists with
// rank (0 = top-1 slot, 1 = top-2 slot) and per-token combine metadata.
// ---------------------------------------------------------------------------
__global__ __launch_bounds__(256) void gating_kernel(
    const float* __restrict__ x, const int* __restrict__ labels,
    const float* __restrict__ gate_W, const float* __restrict__ cbuf,
    int* __restrict__ counts, int* __restrict__ tlist, int* __restrict__ rlist,
    float* __restrict__ wA, float* __restrict__ wB,
    int* __restrict__ eA, int* __restrict__ eB,
    unsigned short* __restrict__ xb, float* __restrict__ out_idx) {
    int wave = threadIdx.x >> 6, lane = threadIdx.x & 63;
    int b = blockIdx.x * 4 + wave;
    const float4* xr  = (const float4*)(x + (size_t)b * DIM);
    const float4* gw4 = (const float4*)gate_W;
    unsigned short* xo = xb + (size_t)b * DIM;
    float acc[8] = {0.f, 0.f, 0.f, 0.f, 0.f, 0.f, 0.f, 0.f};
    for (int c = lane; c < DIM / 4; c += 64) {
        float4 xv = xr[c];
        ushort4 xc = { f2bf(xv.x), f2bf(xv.y), f2bf(xv.z), f2bf(xv.w) };
        *(ushort4*)(xo + 4 * c) = xc;
        #pragma unroll
        for (int e = 0; e < 8; ++e) {
            float4 wv = gw4[e * (2 * DIM / 4) + c];
            acc[e] += xv.x * wv.x + xv.y * wv.y + xv.z * wv.z + xv.w * wv.w;
        }
    }
    #pragma unroll
    for (int off = 32; off; off >>= 1) {
        #pragma unroll
        for (int e = 0; e < 8; ++e) acc[e] += __shfl_down(acc[e], off, 64);
    }
    if (lane == 0) {
        int lbl = labels[b];
        float lg[8];
        #pragma unroll
        for (int e = 0; e < 8; ++e) lg[e] = acc[e] + cbuf[lbl * 8 + e];
        int e0 = 0; float t0 = lg[0];
        #pragma unroll
        for (int e = 1; e < 8; ++e) if (lg[e] > t0) { t0 = lg[e]; e0 = e; }
        int e1 = -1; float t1 = -1e30f;
        #pragma unroll
        for (int e = 0; e < 8; ++e)
            if (e != e0 && lg[e] > t1) { t1 = lg[e]; e1 = e; }
        float w0 = 1.f / (1.f + __expf(t1 - t0));
        float w1 = 1.f - w0;
        int p0 = atomicAdd(&counts[e0], 1);
        int p1 = atomicAdd(&counts[e1], 1);
        tlist[e0 * CAP + p0] = b; rlist[e0 * CAP + p0] = 0;
        tlist[e1 * CAP + p1] = b; rlist[e1 * CAP + p1] = 1;
        wA[b] = w0; wB[b] = w1; eA[b] = e0; eB[b] = e1;
        out_idx[2 * b]     = (float)e0;
        out_idx[2 * b + 1] = (float)e1;
    }
}

// ---------------------------------------------------------------------------
// Pad each expert list to a multiple of BM: token 0, rank 2 (-> trash row).
// ---------------------------------------------------------------------------
__global__ void pad_kernel(const int* __restrict__ counts,
                           int* __restrict__ tlist, int* __restrict__ rlist) {
    int e = blockIdx.x, c = counts[e];
    int padded = (c + BM - 1) & ~(BM - 1);
    int i = c + threadIdx.x;
    if (i < padded) { tlist[e * CAP + i] = 0; rlist[e * CAP + i] = 2; }
}

// ---------------------------------------------------------------------------
// Grouped expert GEMM (proven R0 structure). Distance-1 double-buffered
// global_load_lds. ONE change vs R0: the LDS swizzle is now
// slot ^= (row>>1)&3 (was row&3). Rows are 64 B, so the bank index only
// sees row bit 0; the old swizzle left rows {0,4,8,12} of each read phase
// on identical banks -> 4-way conflict (matches SQ_LDS_BANK_CONFLICT
// ~3.9 extra cyc/ds_read). With (row>>1)&3 each bank is hit exactly 2x
// per 16-lane phase, and 2-way is free.
// ---------------------------------------------------------------------------
__global__ __launch_bounds__(256, 3) void moe_gemm_kernel(
    const unsigned short* __restrict__ xb, const unsigned short* __restrict__ Wb,
    const int* __restrict__ counts, const int* __restrict__ tlist,
    const int* __restrict__ rlist,
    float* __restrict__ out0, float* __restrict__ y1, float* __restrict__ trash) {
    const int e  = blockIdx.z;
    const int m0 = blockIdx.y * BM;
    if (m0 >= counts[e]) return;
    const int n0 = blockIdx.x * BN;

    __shared__ unsigned short As0[BM * BK], As1[BM * BK];   // 8 KB each
    __shared__ unsigned short Bs0[BN * BK], Bs1[BN * BK];
    __shared__ int toks[BM];
    __shared__ unsigned long long rowp[BM];

    const int t = threadIdx.x;
    if (t < BM) {
        int tok = tlist[e * CAP + m0 + t];
        int rk  = rlist[e * CAP + m0 + t];
        toks[t] = tok;
        float* p = (rk == 0) ? out0 + (size_t)tok * HID
                 : (rk == 1) ? y1   + (size_t)tok * HID
                             : trash;
        rowp[t] = (unsigned long long)p;
    }
    __syncthreads();

    const int lane = t & 63, wave = t >> 6;
    const int rowc = lane >> 2;                     // 0..15
    const int colg = lane & 3;
    const int gcol = ((colg ^ ((rowc >> 1) & 3)) * 8);  // swizzled K-group (elems)

    const unsigned short* gA[2];
    const unsigned short* gB[2];
    int ldsoff[2];
    #pragma unroll
    for (int j = 0; j < 2; ++j) {
        int row = wave * 32 + j * 16 + rowc;
        gA[j] = xb + (size_t)toks[row] * DIM + gcol;
        gB[j] = Wb + ((size_t)e * HID + n0 + row) * DIM + gcol;
        ldsoff[j] = (wave * 32 + j * 16) * BK;
    }

    const int wm = wave >> 1, wn = wave & 1;
    const int r = lane & 15, quad = lane >> 4;
    const int pg = ((quad ^ ((r >> 1) & 3)) * 8);   // physical group for frags

    f32x4 acc[4][4] = {};

    auto stage = [&](unsigned short* Ad, unsigned short* Bd, int kstep) {
        const int kc = kstep * BK;
        #pragma unroll
        for (int j = 0; j < 2; ++j) {
            async_copy16(gA[j] + kc, Ad + ldsoff[j]);
            async_copy16(gB[j] + kc, Bd + ldsoff[j]);
        }
    };
    auto compute = [&](const unsigned short* Ab, const unsigned short* Bb) {
        bf16x8 af[4], bfr[4];
        #pragma unroll
        for (int i = 0; i < 4; ++i) {
            af[i]  = *(const bf16x8*)&Ab[(wm * 64 + i * 16 + r) * BK + pg];
            bfr[i] = *(const bf16x8*)&Bb[(wn * 64 + i * 16 + r) * BK + pg];
        }
        #pragma unroll
        for (int im = 0; im < 4; ++im)
            #pragma unroll
            for (int in = 0; in < 4; ++in)
                acc[im][in] = __builtin_amdgcn_mfma_f32_16x16x32_bf16(
                    af[im], bfr[in], acc[im][in], 0, 0, 0);
    };

    stage(As0, Bs0, 0);
    __syncthreads();
    for (int k2 = 0; k2 < KITER; k2 += 2) {
        stage(As1, Bs1, k2 + 1);          // prefetch next stage
        compute(As0, Bs0);                // covers the vmcnt drain below
        __syncthreads();
        if (k2 + 2 < KITER) stage(As0, Bs0, k2 + 2);
        compute(As1, Bs1);
        __syncthreads();
    }

    // Epilogue: plain stores via per-row destination pointers.
    #pragma unroll
    for (int in = 0; in < 4; ++in) {
        int col = n0 + wn * 64 + in * 16 + r;
        #pragma unroll
        for (int im = 0; im < 4; ++im) {
            int rowb = wm * 64 + im * 16 + quad * 4;
            #pragma unroll
            for (int r4 = 0; r4 < 4; ++r4) {
                float* dst = (float*)rowp[rowb + r4];
                dst[col] = acc[im][in][r4];
            }
        }
    }
}

// ---------------------------------------------------------------------------
// out[b] = w0*(y0+bias[e0]) + w1*(y1+bias[e1]),  y0 read in-place from out.
// ---------------------------------------------------------------------------
__global__ __launch_bounds__(256) void combine_kernel(
    const float* __restrict__ y1, const float* __restrict__ eb,
    const float* __restrict__ wA, const float* __restrict__ wB,
    const int* __restrict__ eA, const int* __restrict__ eB,
    float* __restrict__ out) {
    int b = blockIdx.x;
    float w0 = wA[b], w1 = wB[b];
    int e0 = eA[b], e1 = eB[b];
    const float4* y0r = (const float4*)(out + (size_t)b * HID);
    const float4* y1r = (const float4*)(y1 + (size_t)b * HID);
    const float4* b0r = (const float4*)(eb + (size_t)e0 * HID);
    const float4* b1r = (const float4*)(eb + (size_t)e1 * HID);
    float4* o = (float4*)(out + (size_t)b * HID);
    for (int i = threadIdx.x; i < HID / 4; i += 256) {
        float4 a = y0r[i], c = y1r[i], u = b0r[i], v = b1r[i];
        float4 rs;
        rs.x = w0 * (a.x + u.x) + w1 * (c.x + v.x);
        rs.y = w0 * (a.y + u.y) + w1 * (c.y + v.y);
        rs.z = w0 * (a.z + u.z) + w1 * (c.z + v.z);
        rs.w = w0 * (a.w + u.w) + w1 * (c.w + v.w);
        o[i] = rs;
    }
}

// ---------------------------------------------------------------------------
extern "C" void kernel_launch(void* const* d_in, const int* in_sizes, int n_in,
                              void* d_out, int out_size, void* d_ws, size_t ws_size,
                              hipStream_t stream) {
    const float* x        = (const float*)d_in[0];
    const int*   labels   = (const int*)  d_in[1];
    const float* emb      = (const float*)d_in[2];
    const float* gate_W   = (const float*)d_in[3];
    const float* gate_b   = (const float*)d_in[4];
    const float* expert_W = (const float*)d_in[5];
    const float* expert_b = (const float*)d_in[6];
    float* out = (float*)d_out;

    char* ws = (char*)d_ws;
    int*   counts = (int*)ws;                                  // 32 B
    float* cbuf   = (float*)(ws + 256);                        // 96 B
    int*   tlist  = (int*)(ws + 512);                          // 135168 B
    int*   rlist  = (int*)(ws + 512 + 135168);                 // 135168 B
    float* wA     = (float*)(ws + 270848);                     // 16 KB each
    float* wB     = (float*)(ws + 287232);
    int*   eA     = (int*)  (ws + 303616);
    int*   eB     = (int*)  (ws + 320000);
    float* trash  = (float*)(ws + 336384);                     // 16 KB
    float* y1     = (float*)(ws + 352768);                     // 67 MB
    unsigned short* xb = (unsigned short*)(ws + 352768 + (size_t)B_TOK * HID * 4);
    unsigned short* Wb = xb + (size_t)B_TOK * DIM;             // 134 MB
    // total ws use ≈ 208.4 MiB

    hipMemsetAsync(counts, 0, 8 * sizeof(int), stream);

    cvt_kernel<<<(NEXP * HID * DIM) / (8 * 256), 256, 0, stream>>>(
        expert_W, Wb, (long)NEXP * HID * DIM);
    compute_c_kernel<<<6, 256, 0, stream>>>(emb, gate_W, gate_b, cbuf);
    gating_kernel<<<B_TOK / 4, 256, 0, stream>>>(
        x, labels, gate_W, cbuf, counts, tlist, rlist, wA, wB, eA, eB, xb,
        out + (size_t)B_TOK * HID);
    pad_kernel<<<NEXP, BM, 0, stream>>>(counts, tlist, rlist);
    moe_gemm_kernel<<<dim3(HID / BN, B_TOK / BM, NEXP), 256, 0, stream>>>(
        xb, Wb, counts, tlist, rlist, out, y1, trash);
    combine_kernel<<<B_TOK, 256, 0, stream>>>(
        y1, expert_b, wA, wB, eA, eB, out);
}